// Round 7
// baseline (240.614 us; speedup 1.0000x reference)
//
#include <hip/hip_runtime.h>
#include <hip/hip_bf16.h>
#include <hip/hip_fp16.h>

#define HEADS 8
#define DK 64
#define DV 64
#define DM 512
#define ROUNDS 2
#define SEQ 4096
#define BUCKET 64
#define NCHUNK 64
#define BATCH 4
#define GAP_THRESH 0.02f

typedef _Float16 f16;
typedef f16 f16x4 __attribute__((ext_vector_type(4)));
typedef f16 f16x8 __attribute__((ext_vector_type(8)));
typedef float f32x4 __attribute__((ext_vector_type(4)));

#define MFMA16(a, b, c) __builtin_amdgcn_mfma_f32_16x16x32_f16((a), (b), (c), 0, 0, 0)

// ---------------------------------------------------------------------------
// Kernel 1: approximate hash via MFMA with certified error bound.
// UNCHANGED from verified round-5. Tight rows (gap <= 0.02, expected ~0-3 of
// 32768) are flagged; the exact fp64 redo now lives in sort_kernel.
// ---------------------------------------------------------------------------
__global__ __launch_bounds__(256) void hash_approx_kernel(
    const float* __restrict__ q, const float* __restrict__ R,
    int* __restrict__ h_out, unsigned char* __restrict__ flag) {
  int blk = blockIdx.x;  // 2*4*64 = 512
  int stile = blk & 63;
  int b = (blk >> 6) & (BATCH - 1);
  int r = blk >> 8;
  int s0 = stile << 6;
  int rb = r * BATCH + b;

  __shared__ f16 Rh[32 * 520];  // 33280 B
  __shared__ f16 Rl[32 * 520];  // 33280 B

  int tid = threadIdx.x;
  int w = tid >> 6, lane = tid & 63, lo = lane & 15, hi = lane >> 4;

  // ---- stage R (512x32 fp32 -> transposed [m][d] f16 hi/lo), once ----
  const float* rbase = R + (size_t)r * DM * 32;
#pragma unroll
  for (int i = 0; i < 16; ++i) {
    int fi = tid + i * 256;
    float4 rv = *reinterpret_cast<const float4*>(rbase + fi * 4);
    int d = fi >> 3, m0 = (fi & 7) * 4;
    const float* rp = &rv.x;
#pragma unroll
    for (int e = 0; e < 4; ++e) {
      float x = rp[e];
      f16 hx = (f16)x;
      Rh[(m0 + e) * 520 + d] = hx;
      Rl[(m0 + e) * 520 + d] = (f16)(x - (float)hx);
    }
  }
  __syncthreads();

  // ---- MFMA: wave w handles q-rows w*16..+15, 2 n-tiles (m 0-15, 16-31) ----
  int qr = w * 16 + lo;
  const float* qp = q + ((size_t)b * SEQ + s0 + qr) * DM;

  f32x4 acc0 = {0.f, 0.f, 0.f, 0.f}, acc1 = {0.f, 0.f, 0.f, 0.f};
#pragma unroll 4
  for (int ks = 0; ks < 16; ++ks) {
    int k = ks * 32 + hi * 8;
    float4 a0 = *reinterpret_cast<const float4*>(qp + k);
    float4 a1 = *reinterpret_cast<const float4*>(qp + k + 4);
    float av[8] = {a0.x, a0.y, a0.z, a0.w, a1.x, a1.y, a1.z, a1.w};
    f16x8 ahi, alo;
#pragma unroll
    for (int e = 0; e < 8; ++e) {
      f16 hx = (f16)av[e];
      ahi[e] = hx;
      alo[e] = (f16)(av[e] - (float)hx);
    }
    f16x8 bh0 = *reinterpret_cast<const f16x8*>(&Rh[lo * 520 + k]);
    f16x8 bl0 = *reinterpret_cast<const f16x8*>(&Rl[lo * 520 + k]);
    f16x8 bh1 = *reinterpret_cast<const f16x8*>(&Rh[(16 + lo) * 520 + k]);
    f16x8 bl1 = *reinterpret_cast<const f16x8*>(&Rl[(16 + lo) * 520 + k]);
    acc0 = MFMA16(ahi, bh0, acc0);
    acc0 = MFMA16(ahi, bl0, acc0);
    acc0 = MFMA16(alo, bh0, acc0);
    acc1 = MFMA16(ahi, bh1, acc1);
    acc1 = MFMA16(ahi, bl1, acc1);
    acc1 = MFMA16(alo, bh1, acc1);
  }

  // ---- per-row top-2 over 64 candidates [rot, -rot], lowest-index-first ----
#pragma unroll
  for (int rg = 0; rg < 4; ++rg) {
    float c0 = acc0[rg], c1 = acc1[rg];
    float v1 = c0;
    int i1 = lo;
    float v2 = -INFINITY;
    float cv[3] = {c1, -c0, -c1};
    int ci[3] = {16 + lo, 32 + lo, 48 + lo};
#pragma unroll
    for (int c = 0; c < 3; ++c) {
      if (cv[c] > v1) { v2 = v1; v1 = cv[c]; i1 = ci[c]; }
      else v2 = fmaxf(v2, cv[c]);
    }
#pragma unroll
    for (int off = 1; off <= 8; off <<= 1) {
      float ov1 = __shfl_xor(v1, off);
      int oi1 = __shfl_xor(i1, off);
      float ov2 = __shfl_xor(v2, off);
      if (ov1 > v1 || (ov1 == v1 && oi1 < i1)) {
        v2 = fmaxf(v1, ov2);
        v1 = ov1;
        i1 = oi1;
      } else {
        v2 = fmaxf(v2, ov1);
      }
    }
    if (lo == 0) {
      int grow = s0 + w * 16 + hi * 4 + rg;  // verified C-row mapping
      size_t gid = (size_t)rb * SEQ + grow;
      h_out[gid] = i1 + 1;
      flag[gid] = (v1 - v2 <= GAP_THRESH) ? 1 : 0;
    }
  }
}

// ---------------------------------------------------------------------------
// Kernel 2: stable counting sort per (r,b), with fused exact-redo prologue.
// Prologue: scan this rb's 4096 flag bytes; for each tight-gap row (expected
// ~0-2 total) redo the argmax in fp64 with math/order identical to the
// verified hash (chunked ascending partials, deterministic combine), patch
// h in global (for attn) and keep the correction in LDS for local phases.
// Sort body: ballot match-mask ranks, UNCHANGED from verified round-5.
// ---------------------------------------------------------------------------
__global__ __launch_bounds__(256) void sort_kernel(
    int* h, int* __restrict__ sorted_idx, const float* __restrict__ q,
    const float* __restrict__ R, const unsigned char* __restrict__ flag) {
  int rb = blockIdx.x;
  int* hp = h + (size_t)rb * SEQ;
  __shared__ unsigned char hs[SEQ];
  __shared__ unsigned char rs[SEQ];
  __shared__ int tile_cnt[64][64];
  __shared__ int tile_base[64][64];
  __shared__ int bucket_base[64];
  __shared__ int bucket_tot[64];
  __shared__ int nf;
  __shared__ short flist[256];
  __shared__ unsigned char fcorr[256];
  __shared__ double pl[8][33];
  int tid = threadIdx.x;
  int wave = tid >> 6, lane = tid & 63;
  if (tid == 0) nf = 0;
  for (int i = tid; i < 64 * 64; i += 256) ((int*)tile_cnt)[i] = 0;
  __syncthreads();

  // ---- exact-redo prologue ----
  const unsigned char* fp = flag + (size_t)rb * SEQ;
  for (int s = tid; s < SEQ; s += 256)
    if (fp[s]) {
      int i = atomicAdd(&nf, 1);
      if (i < 256) flist[i] = (short)s;
    }
  __syncthreads();
  int n = nf < 256 ? nf : 256;
  if (n) {
    int rr = rb >> 2, bb = rb & (BATCH - 1);
    for (int i = 0; i < n; ++i) {
      int s = flist[i];
      int m = tid & 31, chunk = tid >> 5;
      const float* qp = q + ((size_t)bb * SEQ + s) * DM;
      const float* rp = R + (size_t)rr * DM * 32;
      double part = 0.0;
      for (int dd = 0; dd < 64; ++dd) {
        int d = chunk * 64 + dd;
        part = fma((double)qp[d], (double)rp[(size_t)d * 32 + m], part);
      }
      pl[chunk][m] = part;
      __syncthreads();
      if (tid < 32) {
        double sum = 0.0;
#pragma unroll
        for (int c = 0; c < 8; ++c) sum += pl[c][m];  // ascending, deterministic
        double v = sum;
        int ix = m;
        double nv = -sum;
        if (nv > v) { v = nv; ix = m + 32; }
        for (int off = 1; off <= 16; off <<= 1) {
          double ov = __shfl_xor(v, off);
          int oi = __shfl_xor(ix, off);
          if (ov > v || (ov == v && oi < ix)) { v = ov; ix = oi; }
        }
        if (tid == 0) {
          fcorr[i] = (unsigned char)ix;
          hp[s] = ix + 1;  // global patch for attn (kernel-boundary visible)
        }
      }
      __syncthreads();
    }
  }

  // ---- sort body ----
  for (int t = wave; t < 64; t += 4) {
    int s = (t << 6) + lane;
    int hv = hp[s] - 1;
    for (int j = 0; j < n; ++j)
      if (flist[j] == s) hv = fcorr[j];  // LDS override (belt + suspenders)
    unsigned long long mm = ~0ull;
#pragma unroll
    for (int bit = 0; bit < 6; ++bit) {
      unsigned long long bb = __ballot((hv >> bit) & 1);
      mm &= ((hv >> bit) & 1) ? bb : ~bb;
    }
    int rank = __popcll(mm & ((1ull << lane) - 1ull));
    hs[s] = (unsigned char)hv;
    rs[s] = (unsigned char)rank;
    if (rank == 0) tile_cnt[t][hv] = __popcll(mm);
  }
  __syncthreads();
  if (tid < 64) {
    int bkt = tid;
    int run = 0;
    for (int t = 0; t < 64; ++t) { tile_base[t][bkt] = run; run += tile_cnt[t][bkt]; }
    bucket_tot[bkt] = run;
  }
  __syncthreads();
  if (tid == 0) {
    int run = 0;
    for (int bkt = 0; bkt < 64; ++bkt) { bucket_base[bkt] = run; run += bucket_tot[bkt]; }
  }
  __syncthreads();
  for (int t = wave; t < 64; t += 4) {
    int s = (t << 6) + lane;
    int hv = hs[s];
    int pos = bucket_base[hv] + tile_base[t][hv] + rs[s];
    sorted_idx[(size_t)rb * SEQ + pos] = s;
  }
}

// ---------------------------------------------------------------------------
// Kernel 3: chunked LSH attention on MFMA.
// Changes vs verified round-5 (math identical, layout only):
//  (a) V ds_write deferred to after the softmax barrier -> Vt overlays the
//      dead Kh region. Peak LDS 45056 -> 34816 (+1KB statics) = 4 blocks/CU.
//      V global->reg loads stay early (T14 overlap under QK^T); vreg is held
//      through softmax (+32 VGPR, still <=128 for 4-wave/SIMD occupancy).
//  (b) Vt row-rotation swizzle: byte-in-row = (2l + 16*((dv>>3)&7)) & 255.
//      Write insts go 8-way -> 2 lanes/bank (free, m136); PV b128 reads stay
//      16B-aligned (rotation is a multiple of 16 within the 256B row).
// LDS map: Qh[64][72] @0 (9216), Kh[128][72] @9216 (18432) -- phase A;
//          P fp16 [64 q][272B] @0 (17408), Vt [64 dv][272B] @17408 -- phase B.
// ---------------------------------------------------------------------------
__global__ __launch_bounds__(256) void attn_kernel(
    const float* __restrict__ q, const float* __restrict__ k,
    const float* __restrict__ v, const int* __restrict__ h,
    const int* __restrict__ sidx, float* __restrict__ out, int r,
    int accumulate) {
  int x = blockIdx.x;
  int hd = x & 7;
  int n = (x >> 3) & 63;
  int b = x >> 9;
  int rb = r * BATCH + b;

  __shared__ __align__(16) unsigned char smem[34816];
  __shared__ int orig_w[128];
  __shared__ int hw[128];
  f16* Qh = reinterpret_cast<f16*>(smem);           // [64][72]
  f16* Kh = reinterpret_cast<f16*>(smem + 9216);    // [128][72]
  const int VOFF = 17408;                           // Vt base (phase B)

  int tid = threadIdx.x;
  int wave = tid >> 6;
  int lane = tid & 63;
  int lo = lane & 15;
  int hi = lane >> 4;

  if (tid < 128) {
    int j = tid;
    int sp = (j < 64) ? ((((n + 63) & 63) << 6) + j) : ((n << 6) + (j - 64));
    int orig = sidx[(size_t)rb * SEQ + sp];
    orig_w[j] = orig;
    hw[j] = h[(size_t)rb * SEQ + orig];
  }
  __syncthreads();

  const size_t gbase = (size_t)b * SEQ * DM + hd * 64;

  // ---- stage K (128x64) and Q (64x64) as fp16 ----
  float4 kreg[8], qreg[4];
#pragma unroll
  for (int t = 0; t < 8; ++t) {
    int idx = tid + t * 256;
    int j = idx >> 4, dq = idx & 15;
    kreg[t] = *reinterpret_cast<const float4*>(
        k + gbase + (size_t)orig_w[j] * DM + dq * 4);
  }
#pragma unroll
  for (int t = 0; t < 4; ++t) {
    int idx = tid + t * 256;
    int i = idx >> 4, dq = idx & 15;
    qreg[t] = *reinterpret_cast<const float4*>(
        q + gbase + (size_t)orig_w[64 + i] * DM + dq * 4);
  }
#pragma unroll
  for (int t = 0; t < 8; ++t) {
    int idx = tid + t * 256;
    int j = idx >> 4, dq = idx & 15;
    f16x4 hv = {(f16)kreg[t].x, (f16)kreg[t].y, (f16)kreg[t].z, (f16)kreg[t].w};
    *reinterpret_cast<f16x4*>(&Kh[j * 72 + dq * 4]) = hv;
  }
#pragma unroll
  for (int t = 0; t < 4; ++t) {
    int idx = tid + t * 256;
    int i = idx >> 4, dq = idx & 15;
    f16x4 hv = {(f16)qreg[t].x, (f16)qreg[t].y, (f16)qreg[t].z, (f16)qreg[t].w};
    *reinterpret_cast<f16x4*>(&Qh[i * 72 + dq * 4]) = hv;
  }
  __syncthreads();

  // issue V global loads now; they complete under QK^T (T14)
  float4 vreg[8];
#pragma unroll
  for (int t = 0; t < 8; ++t) {
    int idx = tid + t * 256;
    int l = idx >> 4, dq = idx & 15;
    vreg[t] = *reinterpret_cast<const float4*>(
        v + gbase + (size_t)orig_w[l] * DM + dq * 4);
  }

  // ---- QK^T via MFMA ----
  f32x4 acc[8];
#pragma unroll
  for (int t = 0; t < 8; ++t) acc[t] = (f32x4){0.f, 0.f, 0.f, 0.f};

  int qr_a = wave * 16 + lo;
  f16x8 aq0 = *reinterpret_cast<const f16x8*>(&Qh[qr_a * 72 + hi * 8]);
  f16x8 aq1 = *reinterpret_cast<const f16x8*>(&Qh[qr_a * 72 + 32 + hi * 8]);
#pragma unroll
  for (int t = 0; t < 8; ++t) {
    f16x8 b0 = *reinterpret_cast<const f16x8*>(&Kh[(t * 16 + lo) * 72 + hi * 8]);
    f16x8 b1 = *reinterpret_cast<const f16x8*>(&Kh[(t * 16 + lo) * 72 + 32 + hi * 8]);
    acc[t] = MFMA16(aq0, b0, acc[t]);
    acc[t] = MFMA16(aq1, b1, acc[t]);
  }

  // ---- scale + masks + softmax in registers ----
  int hq[4];
#pragma unroll
  for (int rg = 0; rg < 4; ++rg) hq[rg] = hw[64 + wave * 16 + hi * 4 + rg];
#pragma unroll
  for (int t = 0; t < 8; ++t) {
    int key = t * 16 + lo;
    int hj = hw[key];
#pragma unroll
    for (int rg = 0; rg < 4; ++rg) {
      int qr = wave * 16 + hi * 4 + rg;
      float lg = acc[t][rg] * 0.125f;
      if (hj != hq[rg]) lg = -1e15f;
      if (key == 64 + qr) lg -= 1e5f;
      acc[t][rg] = lg;
    }
  }
  float mx[4] = {-INFINITY, -INFINITY, -INFINITY, -INFINITY};
#pragma unroll
  for (int t = 0; t < 8; ++t)
#pragma unroll
    for (int rg = 0; rg < 4; ++rg) mx[rg] = fmaxf(mx[rg], acc[t][rg]);
#pragma unroll
  for (int off = 1; off <= 8; off <<= 1)
#pragma unroll
    for (int rg = 0; rg < 4; ++rg) mx[rg] = fmaxf(mx[rg], __shfl_xor(mx[rg], off));
  float sm[4] = {0.f, 0.f, 0.f, 0.f};
#pragma unroll
  for (int t = 0; t < 8; ++t)
#pragma unroll
    for (int rg = 0; rg < 4; ++rg) {
      float ev = __expf(acc[t][rg] - mx[rg]);
      acc[t][rg] = ev;
      sm[rg] += ev;
    }
#pragma unroll
  for (int off = 1; off <= 8; off <<= 1)
#pragma unroll
    for (int rg = 0; rg < 4; ++rg) sm[rg] += __shfl_xor(sm[rg], off);
  float inv[4];
#pragma unroll
  for (int rg = 0; rg < 4; ++rg) inv[rg] = 1.0f / sm[rg];

  __syncthreads();  // all Qh/Kh fragment reads complete; phase-B overlay safe

  // ---- write P fp16 [64 q][272B rows] at offset 0 ----
#pragma unroll
  for (int t = 0; t < 8; ++t) {
    int key = t * 16 + lo;
#pragma unroll
    for (int rg = 0; rg < 4; ++rg) {
      int qr = wave * 16 + hi * 4 + rg;
      *reinterpret_cast<f16*>(smem + qr * 272 + key * 2) =
          (f16)(acc[t][rg] * inv[rg]);
    }
  }
  // ---- write V transposed [dv][l], row-rotation swizzled ----
#pragma unroll
  for (int t = 0; t < 8; ++t) {
    int idx = tid + t * 256;
    int l = idx >> 4, dq = idx & 15;
    const float* vp = &vreg[t].x;
#pragma unroll
    for (int c = 0; c < 4; ++c) {
      int dv = dq * 4 + c;
      int off = (l * 2 + (((dv >> 3) & 7) << 4)) & 255;
      *reinterpret_cast<f16*>(smem + VOFF + dv * 272 + off) = (f16)vp[c];
    }
  }
  __syncthreads();

  // ---- P @ V via MFMA ----
  f32x4 o[4];
#pragma unroll
  for (int dt = 0; dt < 4; ++dt) o[dt] = (f32x4){0.f, 0.f, 0.f, 0.f};
#pragma unroll
  for (int lt = 0; lt < 4; ++lt) {
    f16x8 ap = *reinterpret_cast<const f16x8*>(
        smem + qr_a * 272 + lt * 64 + hi * 16);
#pragma unroll
    for (int dt = 0; dt < 4; ++dt) {
      int dvr = dt * 16 + lo;
      int off = (lt * 64 + hi * 16 + (((dvr >> 3) & 7) << 4)) & 255;
      f16x8 bv = *reinterpret_cast<const f16x8*>(smem + VOFF + dvr * 272 + off);
      o[dt] = MFMA16(ap, bv, o[dt]);
    }
  }

  // ---- output ----
#pragma unroll
  for (int dt = 0; dt < 4; ++dt) {
#pragma unroll
    for (int rg = 0; rg < 4; ++rg) {
      int qr = wave * 16 + hi * 4 + rg;
      float* dst = out + gbase + (size_t)orig_w[64 + qr] * DM + dt * 16 + lo;
      if (accumulate) {
        *dst = *dst + o[dt][rg];
      } else {
        *dst = o[dt][rg];
      }
    }
  }
}

extern "C" void kernel_launch(void* const* d_in, const int* in_sizes, int n_in,
                              void* d_out, int out_size, void* d_ws,
                              size_t ws_size, hipStream_t stream) {
  (void)out_size; (void)ws_size;
  const int R_ELEMS = ROUNDS * DM * 32;
  const float *q, *k, *v, *R;
  if (n_in >= 4 && in_sizes[0] == R_ELEMS) {  // defensive; dict order is live
    R = (const float*)d_in[0];
    k = (const float*)d_in[1];
    q = (const float*)d_in[2];
    v = (const float*)d_in[3];
  } else {
    q = (const float*)d_in[0];
    k = (const float*)d_in[1];
    v = (const float*)d_in[2];
    R = (const float*)d_in[3];
  }
  float* out = (float*)d_out;  // REFERENCE OUTPUT IS FP32
  char* ws = (char*)d_ws;
  int* h = (int*)ws;                                          // 128 KB
  int* sidx = (int*)(ws + ROUNDS * BATCH * SEQ * 4);          // 128 KB
  unsigned char* flag = (unsigned char*)(ws + 2 * ROUNDS * BATCH * SEQ * 4);  // 32 KB

  hash_approx_kernel<<<ROUNDS * BATCH * (SEQ / 64), 256, 0, stream>>>(q, R, h, flag);
  sort_kernel<<<ROUNDS * BATCH, 256, 0, stream>>>(h, sidx, q, R, flag);
  attn_kernel<<<BATCH * NCHUNK * HEADS, 256, 0, stream>>>(q, k, v, h, sidx, out, 0, 0);
  attn_kernel<<<BATCH * NCHUNK * HEADS, 256, 0, stream>>>(q, k, v, h, sidx, out, 1, 1);
}

// Round 8
// 204.876 us; speedup vs baseline: 1.1744x; 1.1744x over previous
//
#include <hip/hip_runtime.h>
#include <hip/hip_bf16.h>
#include <hip/hip_fp16.h>

#define HEADS 8
#define DK 64
#define DV 64
#define DM 512
#define ROUNDS 2
#define SEQ 4096
#define BUCKET 64
#define NCHUNK 64
#define BATCH 4
#define GAP_THRESH 0.02f

typedef _Float16 f16;
typedef f16 f16x4 __attribute__((ext_vector_type(4)));
typedef f16 f16x8 __attribute__((ext_vector_type(8)));
typedef float f32x4 __attribute__((ext_vector_type(4)));

#define MFMA16(a, b, c) __builtin_amdgcn_mfma_f32_16x16x32_f16((a), (b), (c), 0, 0, 0)

// ---------------------------------------------------------------------------
// Kernel 1a: approximate hash via MFMA with certified error bound.
// UNCHANGED from verified round-5. ~80 of 32768 rows get flagged (gap stats:
// sigma~22.6, top-2 gap mean ~8 -> P(gap<=0.02) ~ 2.5e-3).
// ---------------------------------------------------------------------------
__global__ __launch_bounds__(256) void hash_approx_kernel(
    const float* __restrict__ q, const float* __restrict__ R,
    int* __restrict__ h_out, unsigned char* __restrict__ flag) {
  int blk = blockIdx.x;  // 2*4*64 = 512
  int stile = blk & 63;
  int b = (blk >> 6) & (BATCH - 1);
  int r = blk >> 8;
  int s0 = stile << 6;
  int rb = r * BATCH + b;

  __shared__ f16 Rh[32 * 520];  // 33280 B
  __shared__ f16 Rl[32 * 520];  // 33280 B

  int tid = threadIdx.x;
  int w = tid >> 6, lane = tid & 63, lo = lane & 15, hi = lane >> 4;

  // ---- stage R (512x32 fp32 -> transposed [m][d] f16 hi/lo), once ----
  const float* rbase = R + (size_t)r * DM * 32;
#pragma unroll
  for (int i = 0; i < 16; ++i) {
    int fi = tid + i * 256;
    float4 rv = *reinterpret_cast<const float4*>(rbase + fi * 4);
    int d = fi >> 3, m0 = (fi & 7) * 4;
    const float* rp = &rv.x;
#pragma unroll
    for (int e = 0; e < 4; ++e) {
      float x = rp[e];
      f16 hx = (f16)x;
      Rh[(m0 + e) * 520 + d] = hx;
      Rl[(m0 + e) * 520 + d] = (f16)(x - (float)hx);
    }
  }
  __syncthreads();

  // ---- MFMA: wave w handles q-rows w*16..+15, 2 n-tiles (m 0-15, 16-31) ----
  int qr = w * 16 + lo;
  const float* qp = q + ((size_t)b * SEQ + s0 + qr) * DM;

  f32x4 acc0 = {0.f, 0.f, 0.f, 0.f}, acc1 = {0.f, 0.f, 0.f, 0.f};
#pragma unroll 4
  for (int ks = 0; ks < 16; ++ks) {
    int k = ks * 32 + hi * 8;
    float4 a0 = *reinterpret_cast<const float4*>(qp + k);
    float4 a1 = *reinterpret_cast<const float4*>(qp + k + 4);
    float av[8] = {a0.x, a0.y, a0.z, a0.w, a1.x, a1.y, a1.z, a1.w};
    f16x8 ahi, alo;
#pragma unroll
    for (int e = 0; e < 8; ++e) {
      f16 hx = (f16)av[e];
      ahi[e] = hx;
      alo[e] = (f16)(av[e] - (float)hx);
    }
    f16x8 bh0 = *reinterpret_cast<const f16x8*>(&Rh[lo * 520 + k]);
    f16x8 bl0 = *reinterpret_cast<const f16x8*>(&Rl[lo * 520 + k]);
    f16x8 bh1 = *reinterpret_cast<const f16x8*>(&Rh[(16 + lo) * 520 + k]);
    f16x8 bl1 = *reinterpret_cast<const f16x8*>(&Rl[(16 + lo) * 520 + k]);
    acc0 = MFMA16(ahi, bh0, acc0);
    acc0 = MFMA16(ahi, bl0, acc0);
    acc0 = MFMA16(alo, bh0, acc0);
    acc1 = MFMA16(ahi, bh1, acc1);
    acc1 = MFMA16(ahi, bl1, acc1);
    acc1 = MFMA16(alo, bh1, acc1);
  }

  // ---- per-row top-2 over 64 candidates [rot, -rot], lowest-index-first ----
#pragma unroll
  for (int rg = 0; rg < 4; ++rg) {
    float c0 = acc0[rg], c1 = acc1[rg];
    float v1 = c0;
    int i1 = lo;
    float v2 = -INFINITY;
    float cv[3] = {c1, -c0, -c1};
    int ci[3] = {16 + lo, 32 + lo, 48 + lo};
#pragma unroll
    for (int c = 0; c < 3; ++c) {
      if (cv[c] > v1) { v2 = v1; v1 = cv[c]; i1 = ci[c]; }
      else v2 = fmaxf(v2, cv[c]);
    }
#pragma unroll
    for (int off = 1; off <= 8; off <<= 1) {
      float ov1 = __shfl_xor(v1, off);
      int oi1 = __shfl_xor(i1, off);
      float ov2 = __shfl_xor(v2, off);
      if (ov1 > v1 || (ov1 == v1 && oi1 < i1)) {
        v2 = fmaxf(v1, ov2);
        v1 = ov1;
        i1 = oi1;
      } else {
        v2 = fmaxf(v2, ov1);
      }
    }
    if (lo == 0) {
      int grow = s0 + w * 16 + hi * 4 + rg;  // verified C-row mapping
      size_t gid = (size_t)rb * SEQ + grow;
      h_out[gid] = i1 + 1;
      flag[gid] = (v1 - v2 <= GAP_THRESH) ? 1 : 0;
    }
  }
}

// ---------------------------------------------------------------------------
// Kernel 1b: exact fp64 redo for flagged queries. RESTORED round-5 version:
// 512 blocks, each handles only its own 64-row window -> the ~80 flagged
// rows are processed in parallel (<=1-2 per block). Round-6's fusion into
// the 8-block sort serialized them (~10/block x ~5us chain = 50us) -- the
// measured regression. fp64, deterministic ascending order.
// ---------------------------------------------------------------------------
__global__ __launch_bounds__(256) void hash_exact_kernel(
    const float* __restrict__ q, const float* __restrict__ R,
    const unsigned char* __restrict__ flag, int* __restrict__ h_out) {
  int g0 = blockIdx.x * 64;
  __shared__ int nf;
  __shared__ unsigned char list[64];
  __shared__ double pl[8][33];
  int tid = threadIdx.x;
  if (tid == 0) nf = 0;
  __syncthreads();
  if (tid < 64 && flag[g0 + tid]) {
    int idx = atomicAdd(&nf, 1);
    list[idx] = (unsigned char)tid;
  }
  __syncthreads();
  int n = nf;
  for (int i = 0; i < n; ++i) {
    int g = g0 + list[i];
    int rb = g >> 12, s = g & (SEQ - 1);
    int r = rb >> 2, b = rb & (BATCH - 1);
    int m = tid & 31, chunk = tid >> 5;
    const float* qp = q + ((size_t)b * SEQ + s) * DM;
    const float* rp = R + (size_t)r * DM * 32;
    double part = 0.0;
    for (int dd = 0; dd < 64; ++dd) {
      int d = chunk * 64 + dd;
      part = fma((double)qp[d], (double)rp[(size_t)d * 32 + m], part);
    }
    pl[chunk][m] = part;
    __syncthreads();
    if (tid < 32) {
      double sum = 0.0;
#pragma unroll
      for (int c = 0; c < 8; ++c) sum += pl[c][m];  // ascending, deterministic
      double v = sum;
      int ix = m;
      double nv = -sum;
      if (nv > v) { v = nv; ix = m + 32; }
      for (int off = 1; off <= 16; off <<= 1) {
        double ov = __shfl_xor(v, off);
        int oi = __shfl_xor(ix, off);
        if (ov > v || (ov == v && oi < ix)) { v = ov; ix = oi; }
      }
      if (tid == 0) h_out[g] = ix + 1;
    }
    __syncthreads();
  }
}

// ---------------------------------------------------------------------------
// Kernel 2: stable counting sort (ballot match-mask). RESTORED round-5
// version (no prologue, no override loop).
// ---------------------------------------------------------------------------
__global__ __launch_bounds__(256) void sort_kernel(const int* __restrict__ h,
                                                   int* __restrict__ sorted_idx) {
  int rb = blockIdx.x;
  const int* hp = h + (size_t)rb * SEQ;
  __shared__ unsigned char hs[SEQ];
  __shared__ unsigned char rs[SEQ];
  __shared__ int tile_cnt[64][64];
  __shared__ int tile_base[64][64];
  __shared__ int bucket_base[64];
  __shared__ int bucket_tot[64];
  int tid = threadIdx.x;
  int wave = tid >> 6, lane = tid & 63;
  for (int i = tid; i < 64 * 64; i += 256) ((int*)tile_cnt)[i] = 0;
  __syncthreads();
  for (int t = wave; t < 64; t += 4) {
    int s = (t << 6) + lane;
    int hv = hp[s] - 1;
    unsigned long long mm = ~0ull;
#pragma unroll
    for (int bit = 0; bit < 6; ++bit) {
      unsigned long long bb = __ballot((hv >> bit) & 1);
      mm &= ((hv >> bit) & 1) ? bb : ~bb;
    }
    int rank = __popcll(mm & ((1ull << lane) - 1ull));
    hs[s] = (unsigned char)hv;
    rs[s] = (unsigned char)rank;
    if (rank == 0) tile_cnt[t][hv] = __popcll(mm);
  }
  __syncthreads();
  if (tid < 64) {
    int bkt = tid;
    int run = 0;
    for (int t = 0; t < 64; ++t) { tile_base[t][bkt] = run; run += tile_cnt[t][bkt]; }
    bucket_tot[bkt] = run;
  }
  __syncthreads();
  if (tid == 0) {
    int run = 0;
    for (int bkt = 0; bkt < 64; ++bkt) { bucket_base[bkt] = run; run += bucket_tot[bkt]; }
  }
  __syncthreads();
  for (int t = wave; t < 64; t += 4) {
    int s = (t << 6) + lane;
    int hv = hs[s];
    int pos = bucket_base[hv] + tile_base[t][hv] + rs[s];
    sorted_idx[(size_t)rb * SEQ + pos] = s;
  }
}

// ---------------------------------------------------------------------------
// Kernel 3: chunked LSH attention on MFMA. UNCHANGED from round-6 (verified):
// deferred V ds_write (Vt overlays dead Kh; 34816 B -> 4 blocks/CU) and
// row-rotation swizzled Vt (write insts 2 lanes/bank).
// ---------------------------------------------------------------------------
__global__ __launch_bounds__(256) void attn_kernel(
    const float* __restrict__ q, const float* __restrict__ k,
    const float* __restrict__ v, const int* __restrict__ h,
    const int* __restrict__ sidx, float* __restrict__ out, int r,
    int accumulate) {
  int x = blockIdx.x;
  int hd = x & 7;
  int n = (x >> 3) & 63;
  int b = x >> 9;
  int rb = r * BATCH + b;

  __shared__ __align__(16) unsigned char smem[34816];
  __shared__ int orig_w[128];
  __shared__ int hw[128];
  f16* Qh = reinterpret_cast<f16*>(smem);           // [64][72]
  f16* Kh = reinterpret_cast<f16*>(smem + 9216);    // [128][72]
  const int VOFF = 17408;                           // Vt base (phase B)

  int tid = threadIdx.x;
  int wave = tid >> 6;
  int lane = tid & 63;
  int lo = lane & 15;
  int hi = lane >> 4;

  if (tid < 128) {
    int j = tid;
    int sp = (j < 64) ? ((((n + 63) & 63) << 6) + j) : ((n << 6) + (j - 64));
    int orig = sidx[(size_t)rb * SEQ + sp];
    orig_w[j] = orig;
    hw[j] = h[(size_t)rb * SEQ + orig];
  }
  __syncthreads();

  const size_t gbase = (size_t)b * SEQ * DM + hd * 64;

  // ---- stage K (128x64) and Q (64x64) as fp16 ----
  float4 kreg[8], qreg[4];
#pragma unroll
  for (int t = 0; t < 8; ++t) {
    int idx = tid + t * 256;
    int j = idx >> 4, dq = idx & 15;
    kreg[t] = *reinterpret_cast<const float4*>(
        k + gbase + (size_t)orig_w[j] * DM + dq * 4);
  }
#pragma unroll
  for (int t = 0; t < 4; ++t) {
    int idx = tid + t * 256;
    int i = idx >> 4, dq = idx & 15;
    qreg[t] = *reinterpret_cast<const float4*>(
        q + gbase + (size_t)orig_w[64 + i] * DM + dq * 4);
  }
#pragma unroll
  for (int t = 0; t < 8; ++t) {
    int idx = tid + t * 256;
    int j = idx >> 4, dq = idx & 15;
    f16x4 hv = {(f16)kreg[t].x, (f16)kreg[t].y, (f16)kreg[t].z, (f16)kreg[t].w};
    *reinterpret_cast<f16x4*>(&Kh[j * 72 + dq * 4]) = hv;
  }
#pragma unroll
  for (int t = 0; t < 4; ++t) {
    int idx = tid + t * 256;
    int i = idx >> 4, dq = idx & 15;
    f16x4 hv = {(f16)qreg[t].x, (f16)qreg[t].y, (f16)qreg[t].z, (f16)qreg[t].w};
    *reinterpret_cast<f16x4*>(&Qh[i * 72 + dq * 4]) = hv;
  }
  __syncthreads();

  // issue V global loads now; they complete under QK^T (T14)
  float4 vreg[8];
#pragma unroll
  for (int t = 0; t < 8; ++t) {
    int idx = tid + t * 256;
    int l = idx >> 4, dq = idx & 15;
    vreg[t] = *reinterpret_cast<const float4*>(
        v + gbase + (size_t)orig_w[l] * DM + dq * 4);
  }

  // ---- QK^T via MFMA ----
  f32x4 acc[8];
#pragma unroll
  for (int t = 0; t < 8; ++t) acc[t] = (f32x4){0.f, 0.f, 0.f, 0.f};

  int qr_a = wave * 16 + lo;
  f16x8 aq0 = *reinterpret_cast<const f16x8*>(&Qh[qr_a * 72 + hi * 8]);
  f16x8 aq1 = *reinterpret_cast<const f16x8*>(&Qh[qr_a * 72 + 32 + hi * 8]);
#pragma unroll
  for (int t = 0; t < 8; ++t) {
    f16x8 b0 = *reinterpret_cast<const f16x8*>(&Kh[(t * 16 + lo) * 72 + hi * 8]);
    f16x8 b1 = *reinterpret_cast<const f16x8*>(&Kh[(t * 16 + lo) * 72 + 32 + hi * 8]);
    acc[t] = MFMA16(aq0, b0, acc[t]);
    acc[t] = MFMA16(aq1, b1, acc[t]);
  }

  // ---- scale + masks + softmax in registers ----
  int hq[4];
#pragma unroll
  for (int rg = 0; rg < 4; ++rg) hq[rg] = hw[64 + wave * 16 + hi * 4 + rg];
#pragma unroll
  for (int t = 0; t < 8; ++t) {
    int key = t * 16 + lo;
    int hj = hw[key];
#pragma unroll
    for (int rg = 0; rg < 4; ++rg) {
      int qr = wave * 16 + hi * 4 + rg;
      float lg = acc[t][rg] * 0.125f;
      if (hj != hq[rg]) lg = -1e15f;
      if (key == 64 + qr) lg -= 1e5f;
      acc[t][rg] = lg;
    }
  }
  float mx[4] = {-INFINITY, -INFINITY, -INFINITY, -INFINITY};
#pragma unroll
  for (int t = 0; t < 8; ++t)
#pragma unroll
    for (int rg = 0; rg < 4; ++rg) mx[rg] = fmaxf(mx[rg], acc[t][rg]);
#pragma unroll
  for (int off = 1; off <= 8; off <<= 1)
#pragma unroll
    for (int rg = 0; rg < 4; ++rg) mx[rg] = fmaxf(mx[rg], __shfl_xor(mx[rg], off));
  float sm[4] = {0.f, 0.f, 0.f, 0.f};
#pragma unroll
  for (int t = 0; t < 8; ++t)
#pragma unroll
    for (int rg = 0; rg < 4; ++rg) {
      float ev = __expf(acc[t][rg] - mx[rg]);
      acc[t][rg] = ev;
      sm[rg] += ev;
    }
#pragma unroll
  for (int off = 1; off <= 8; off <<= 1)
#pragma unroll
    for (int rg = 0; rg < 4; ++rg) sm[rg] += __shfl_xor(sm[rg], off);
  float inv[4];
#pragma unroll
  for (int rg = 0; rg < 4; ++rg) inv[rg] = 1.0f / sm[rg];

  __syncthreads();  // all Qh/Kh fragment reads complete; phase-B overlay safe

  // ---- write P fp16 [64 q][272B rows] at offset 0 ----
#pragma unroll
  for (int t = 0; t < 8; ++t) {
    int key = t * 16 + lo;
#pragma unroll
    for (int rg = 0; rg < 4; ++rg) {
      int qr = wave * 16 + hi * 4 + rg;
      *reinterpret_cast<f16*>(smem + qr * 272 + key * 2) =
          (f16)(acc[t][rg] * inv[rg]);
    }
  }
  // ---- write V transposed [dv][l], row-rotation swizzled ----
#pragma unroll
  for (int t = 0; t < 8; ++t) {
    int idx = tid + t * 256;
    int l = idx >> 4, dq = idx & 15;
    const float* vp = &vreg[t].x;
#pragma unroll
    for (int c = 0; c < 4; ++c) {
      int dv = dq * 4 + c;
      int off = (l * 2 + (((dv >> 3) & 7) << 4)) & 255;
      *reinterpret_cast<f16*>(smem + VOFF + dv * 272 + off) = (f16)vp[c];
    }
  }
  __syncthreads();

  // ---- P @ V via MFMA ----
  f32x4 o[4];
#pragma unroll
  for (int dt = 0; dt < 4; ++dt) o[dt] = (f32x4){0.f, 0.f, 0.f, 0.f};
#pragma unroll
  for (int lt = 0; lt < 4; ++lt) {
    f16x8 ap = *reinterpret_cast<const f16x8*>(
        smem + qr_a * 272 + lt * 64 + hi * 16);
#pragma unroll
    for (int dt = 0; dt < 4; ++dt) {
      int dvr = dt * 16 + lo;
      int off = (lt * 64 + hi * 16 + (((dvr >> 3) & 7) << 4)) & 255;
      f16x8 bv = *reinterpret_cast<const f16x8*>(smem + VOFF + dvr * 272 + off);
      o[dt] = MFMA16(ap, bv, o[dt]);
    }
  }

  // ---- output ----
#pragma unroll
  for (int dt = 0; dt < 4; ++dt) {
#pragma unroll
    for (int rg = 0; rg < 4; ++rg) {
      int qr = wave * 16 + hi * 4 + rg;
      float* dst = out + gbase + (size_t)orig_w[64 + qr] * DM + dt * 16 + lo;
      if (accumulate) {
        *dst = *dst + o[dt][rg];
      } else {
        *dst = o[dt][rg];
      }
    }
  }
}

extern "C" void kernel_launch(void* const* d_in, const int* in_sizes, int n_in,
                              void* d_out, int out_size, void* d_ws,
                              size_t ws_size, hipStream_t stream) {
  (void)out_size; (void)ws_size;
  const int R_ELEMS = ROUNDS * DM * 32;
  const float *q, *k, *v, *R;
  if (n_in >= 4 && in_sizes[0] == R_ELEMS) {  // defensive; dict order is live
    R = (const float*)d_in[0];
    k = (const float*)d_in[1];
    q = (const float*)d_in[2];
    v = (const float*)d_in[3];
  } else {
    q = (const float*)d_in[0];
    k = (const float*)d_in[1];
    v = (const float*)d_in[2];
    R = (const float*)d_in[3];
  }
  float* out = (float*)d_out;  // REFERENCE OUTPUT IS FP32
  char* ws = (char*)d_ws;
  int* h = (int*)ws;                                          // 128 KB
  int* sidx = (int*)(ws + ROUNDS * BATCH * SEQ * 4);          // 128 KB
  unsigned char* flag = (unsigned char*)(ws + 2 * ROUNDS * BATCH * SEQ * 4);  // 32 KB

  hash_approx_kernel<<<ROUNDS * BATCH * (SEQ / 64), 256, 0, stream>>>(q, R, h, flag);
  hash_exact_kernel<<<ROUNDS * BATCH * (SEQ / 64), 256, 0, stream>>>(q, R, flag, h);
  sort_kernel<<<ROUNDS * BATCH, 256, 0, stream>>>(h, sidx);
  attn_kernel<<<BATCH * NCHUNK * HEADS, 256, 0, stream>>>(q, k, v, h, sidx, out, 0, 0);
  attn_kernel<<<BATCH * NCHUNK * HEADS, 256, 0, stream>>>(q, k, v, h, sidx, out, 1, 1);
}